// Round 4
// baseline (448.707 us; speedup 1.0000x reference)
//
#include <hip/hip_runtime.h>
#include <math.h>

#define NN 100000
#define NE 1600000
#define BN_EPS 1e-5f
#define NB 782            // buckets of 128 nodes
#define EPB 4096
#define NEB ((NE + EPB - 1) / EPB)   // 391

typedef short bf16x8 __attribute__((ext_vector_type(8)));
typedef float f32x4 __attribute__((ext_vector_type(4)));
typedef unsigned short ushort;
typedef ushort us8 __attribute__((ext_vector_type(8)));
typedef ushort us4 __attribute__((ext_vector_type(4)));

__device__ __forceinline__ ushort f2bf(float f) {
    unsigned u = __float_as_uint(f);
    unsigned r = (u + 0x7FFFu + ((u >> 16) & 1u)) >> 16;
    return (ushort)r;
}
__device__ __forceinline__ float bf2f(ushort h) { return __uint_as_float(((unsigned)h) << 16); }

// ---------------- CSR build via dst-buckets ----------------
__global__ __launch_bounds__(256) void bhist_k(const int* __restrict__ dst, int* __restrict__ bcnt) {
    __shared__ int h[NB];
    for (int i = threadIdx.x; i < NB; i += 256) h[i] = 0;
    __syncthreads();
    int base = blockIdx.x * EPB;
    for (int i = threadIdx.x; i < EPB; i += 256) {
        int e = base + i;
        if (e < NE) atomicAdd(&h[dst[e] >> 7], 1);
    }
    __syncthreads();
    for (int i = threadIdx.x; i < NB; i += 256) {
        int c = h[i];
        if (c) atomicAdd(&bcnt[i], c);
    }
}

__global__ __launch_bounds__(1024) void bscan_k(const int* __restrict__ bcnt, int* __restrict__ bstart,
                                                int* __restrict__ bcur) {
    __shared__ int s[1024];
    int t = threadIdx.x;
    int v = (t < NB) ? bcnt[t] : 0;
    s[t] = v;
    __syncthreads();
    for (int off = 1; off < 1024; off <<= 1) {
        int u = (t >= off) ? s[t - off] : 0;
        __syncthreads();
        s[t] += u;
        __syncthreads();
    }
    int ex = s[t] - v;
    if (t <= NB) bstart[t] = ex;
    if (t < NB) bcur[t] = ex;
}

__global__ __launch_bounds__(256) void bscat_k(const int* __restrict__ ei, int* __restrict__ bcur,
                                               unsigned* __restrict__ packed) {
    __shared__ int h[NB];
    for (int i = threadIdx.x; i < NB; i += 256) h[i] = 0;
    __syncthreads();
    int base = blockIdx.x * EPB;
    for (int i = threadIdx.x; i < EPB; i += 256) {
        int e = base + i;
        if (e < NE) atomicAdd(&h[ei[NE + e] >> 7], 1);
    }
    __syncthreads();
    for (int i = threadIdx.x; i < NB; i += 256) {
        int c = h[i];
        if (c) h[i] = atomicAdd(&bcur[i], c);
    }
    __syncthreads();
    for (int i = threadIdx.x; i < EPB; i += 256) {
        int e = base + i;
        if (e < NE) {
            int d = ei[NE + e];
            int b = d >> 7;
            int pos = atomicAdd(&h[b], 1);
            packed[pos] = (unsigned)ei[e] | ((unsigned)(d & 127) << 17);
        }
    }
}

__global__ __launch_bounds__(256) void csr_k(const unsigned* __restrict__ packed,
                                             const int* __restrict__ bstart,
                                             int* __restrict__ rp, int* __restrict__ col) {
    __shared__ int hc[128], hb[128], sc[128];
    int t = threadIdx.x, b = blockIdx.x;
    int s0 = bstart[b], nb = bstart[b + 1] - s0;
    if (t < 128) hc[t] = 0;
    __syncthreads();
    for (int i = t; i < nb; i += 256) {
        unsigned u = packed[s0 + i];
        atomicAdd(&hc[u >> 17], 1);
    }
    __syncthreads();
    if (t < 128) sc[t] = hc[t];
    __syncthreads();
    for (int off = 1; off < 128; off <<= 1) {
        int u = 0;
        if (t < 128 && t >= off) u = sc[t - off];
        __syncthreads();
        if (t < 128) sc[t] += u;
        __syncthreads();
    }
    if (t < 128) {
        int ex = s0 + sc[t] - hc[t];
        int node = b * 128 + t;
        if (node < NN) rp[node] = ex;
        hb[t] = ex;
    }
    if (b == 0 && t == 0) rp[NN] = NE;
    __syncthreads();
    for (int i = t; i < nb; i += 256) {
        unsigned u = packed[s0 + i];
        int pos = atomicAdd(&hb[u >> 17], 1);
        col[pos] = (int)(u & 0x1FFFFu);
    }
}

// ---------------- converts ----------------
__global__ __launch_bounds__(256) void cvtx_k(const float* __restrict__ x, ushort* __restrict__ xb) {
    int i = blockIdx.x * 256 + threadIdx.x;
    float4 v = ((const float4*)x)[i];
    us4 o;
    o[0] = f2bf(v.x); o[1] = f2bf(v.y); o[2] = f2bf(v.z); o[3] = f2bf(v.w);
    ((us4*)xb)[i] = o;
}

// pack W [128][DOUT] fp32 -> fragment-linear bf16
template <int DOUT>
__global__ __launch_bounds__(256) void packw_k(const float* __restrict__ W, ushort* __restrict__ Wf) {
    constexpr int NT = DOUT / 16;
    int idx = blockIdx.x * 256 + threadIdx.x;
    if (idx >= 4 * NT * 64) return;
    int l = idx & 63;
    int nt = (idx >> 6) % NT;
    int kt = idx / (NT * 64);
    int colw = nt * 16 + (l & 15);
    int k0 = kt * 32 + (l >> 4) * 8;
    us8 o;
#pragma unroll
    for (int e = 0; e < 8; ++e) o[e] = f2bf(W[(k0 + e) * DOUT + colw]);
    ((us8*)Wf)[idx] = o;
}

// ---------------- fused layer: gather-agg -> MLP -> epilogue ----------------
// 256 threads = 4 waves, 64 rows/block, wave w owns rows [R0, R0+16). No barriers.
// Lane l gathers row (l&15), 16B chunks (l>>4)+4t -> agg lands directly in A-frags.
// FINAL=0: BN+relu+residual -> bf16 outb.  FINAL=1: log_softmax -> fp32 outf.
template <int DOUT, int FINAL>
__global__ __launch_bounds__(256) void fused_k(
    const ushort* __restrict__ X, const int* __restrict__ rp, const int* __restrict__ col,
    const ushort* __restrict__ W1f, const ushort* __restrict__ W2f,
    const float* __restrict__ b1, const float* __restrict__ b2,
    const float* __restrict__ bng, const float* __restrict__ bnb,
    const float* __restrict__ bnm, const float* __restrict__ bnv,
    ushort* __restrict__ outb, float* __restrict__ outf) {
    constexpr int NT2 = DOUT / 16;
    __shared__ ushort hlds[4][2048];   // 4KB per wave: h tile 16 rows x 128 cols, XOR-swizzled
    const int t = threadIdx.x;
    const int w = t >> 6, l = t & 63;
    const int lrow = l & 15, lchk = l >> 4;
    const int R0 = blockIdx.x * 64 + w * 16;
    if (R0 >= NN) return;             // wave-uniform (NN % 16 == 0), no barriers in kernel
    const int row = R0 + lrow;

    // ---- gather-aggregate into registers ----
    const us8* __restrict__ xv = (const us8*)X;
    float a[4][8];
#pragma unroll
    for (int tt = 0; tt < 4; ++tt) {
        us8 v = xv[(size_t)row * 16 + tt * 4 + lchk];
#pragma unroll
        for (int e = 0; e < 8; ++e) a[tt][e] = bf2f(v[e]);
    }
    int p = rp[row];
    const int pe = rp[row + 1];
    for (; p + 1 < pe; p += 2) {
        int s0 = col[p], s1 = col[p + 1];
        us8 g0v[4], g1v[4];
#pragma unroll
        for (int tt = 0; tt < 4; ++tt) g0v[tt] = xv[(size_t)s0 * 16 + tt * 4 + lchk];
#pragma unroll
        for (int tt = 0; tt < 4; ++tt) g1v[tt] = xv[(size_t)s1 * 16 + tt * 4 + lchk];
#pragma unroll
        for (int tt = 0; tt < 4; ++tt)
#pragma unroll
            for (int e = 0; e < 8; ++e) a[tt][e] += bf2f(g0v[tt][e]) + bf2f(g1v[tt][e]);
    }
    if (p < pe) {
        int s0 = col[p];
#pragma unroll
        for (int tt = 0; tt < 4; ++tt) {
            us8 g = xv[(size_t)s0 * 16 + tt * 4 + lchk];
#pragma unroll
            for (int e = 0; e < 8; ++e) a[tt][e] += bf2f(g[e]);
        }
    }
    // agg -> A-frags (row lrow, k = kt*32 + lchk*8 .. +8)
    bf16x8 af[4];
#pragma unroll
    for (int tt = 0; tt < 4; ++tt)
#pragma unroll
        for (int e = 0; e < 8; ++e) af[tt][e] = (short)f2bf(a[tt][e]);

    // ---- stage 1: h = relu(agg @ W1 + b1) ----
    f32x4 acc1[8];
#pragma unroll
    for (int nt = 0; nt < 8; ++nt) acc1[nt] = f32x4{0.f, 0.f, 0.f, 0.f};
    const bf16x8* __restrict__ w1p = (const bf16x8*)W1f;
#pragma unroll
    for (int kt = 0; kt < 4; ++kt)
#pragma unroll
        for (int nt = 0; nt < 8; ++nt)
            acc1[nt] = __builtin_amdgcn_mfma_f32_16x16x32_bf16(af[kt], w1p[(kt * 8 + nt) * 64 + l], acc1[nt], 0, 0, 0);

    ushort* hb = hlds[w];
#pragma unroll
    for (int nt = 0; nt < 8; ++nt) {
        int colb = nt * 16 + lrow;
        float bias = b1[colb];
#pragma unroll
        for (int r = 0; r < 4; ++r) {
            int rr = lchk * 4 + r;
            float hv = fmaxf(acc1[nt][r] + bias, 0.f);
            int byte = (rr * 256 + colb * 2) ^ ((rr & 7) << 4);
            *(ushort*)((char*)hb + byte) = f2bf(hv);
        }
    }

    // ---- stage 2: acc2 = h @ W2 (wave-private h, in-order DS => no barrier) ----
    f32x4 acc2[NT2];
#pragma unroll
    for (int nt = 0; nt < NT2; ++nt) acc2[nt] = f32x4{0.f, 0.f, 0.f, 0.f};
    const bf16x8* __restrict__ w2p = (const bf16x8*)W2f;
#pragma unroll
    for (int kt = 0; kt < 4; ++kt) {
        int byte = (lrow * 256 + (kt * 32 + lchk * 8) * 2) ^ ((lrow & 7) << 4);
        bf16x8 hf = *(const bf16x8*)((char*)hb + byte);
#pragma unroll
        for (int nt = 0; nt < NT2; ++nt)
            acc2[nt] = __builtin_amdgcn_mfma_f32_16x16x32_bf16(hf, w2p[(kt * NT2 + nt) * 64 + l], acc2[nt], 0, 0, 0);
    }

    // ---- epilogue ----
    if constexpr (FINAL == 0) {
#pragma unroll
        for (int nt = 0; nt < NT2; ++nt) {
            int colb = nt * 16 + lrow;
            float sc = bng[colb] * rsqrtf(bnv[colb] + BN_EPS);
            float of = (b2[colb] - bnm[colb]) * sc + bnb[colb];
#pragma unroll
            for (int r = 0; r < 4; ++r) {
                int grow = R0 + lchk * 4 + r;
                float xr = bf2f(X[(size_t)grow * 128 + colb]);
                float o = fmaxf(acc2[nt][r] * sc + of, 0.f) + xr;
                outb[(size_t)grow * 128 + colb] = f2bf(o);
            }
        }
    } else {
        float bb[4];
#pragma unroll
        for (int nt = 0; nt < 4; ++nt) bb[nt] = b2[nt * 16 + lrow];
#pragma unroll
        for (int r = 0; r < 4; ++r) {
            float v0 = acc2[0][r] + bb[0], v1 = acc2[1][r] + bb[1];
            float v2 = acc2[2][r] + bb[2], v3 = acc2[3][r] + bb[3];
            float mx = fmaxf(fmaxf(v0, v1), fmaxf(v2, v3));
            for (int d = 1; d < 16; d <<= 1) mx = fmaxf(mx, __shfl_xor(mx, d));
            float sm = expf(v0 - mx) + expf(v1 - mx) + expf(v2 - mx) + expf(v3 - mx);
            for (int d = 1; d < 16; d <<= 1) sm += __shfl_xor(sm, d);
            float L = mx + logf(sm);
            int grow = R0 + lchk * 4 + r;
            outf[(size_t)grow * 64 + 0 + lrow] = v0 - L;
            outf[(size_t)grow * 64 + 16 + lrow] = v1 - L;
            outf[(size_t)grow * 64 + 32 + lrow] = v2 - L;
            outf[(size_t)grow * 64 + 48 + lrow] = v3 - L;
        }
    }
}

extern "C" void kernel_launch(void* const* d_in, const int* in_sizes, int n_in,
                              void* d_out, int out_size, void* d_ws, size_t ws_size,
                              hipStream_t stream) {
    const float* x = (const float*)d_in[0];
    const int* ei = (const int*)d_in[1];
    const float* W1_0 = (const float*)d_in[2];
    const float* b1_0 = (const float*)d_in[3];
    const float* W2_0 = (const float*)d_in[4];
    const float* b2_0 = (const float*)d_in[5];
    const float* W1_1 = (const float*)d_in[6];
    const float* b1_1 = (const float*)d_in[7];
    const float* W2_1 = (const float*)d_in[8];
    const float* b2_1 = (const float*)d_in[9];
    const float* W1_2 = (const float*)d_in[10];
    const float* b1_2 = (const float*)d_in[11];
    const float* W2_2 = (const float*)d_in[12];
    const float* b2_2 = (const float*)d_in[13];
    const float* g0 = (const float*)d_in[14];
    const float* be0 = (const float*)d_in[15];
    const float* m0 = (const float*)d_in[16];
    const float* v0 = (const float*)d_in[17];
    const float* g1 = (const float*)d_in[18];
    const float* be1 = (const float*)d_in[19];
    const float* m1 = (const float*)d_in[20];
    const float* v1 = (const float*)d_in[21];
    float* out = (float*)d_out;

    // ws layout (bytes): xb0 25.6M | xb1 25.6M (packed overlays, transient pre-layer0)
    // | rp 400,128 | col 6.4M | bstart 4K | bcnt 4K | bcur 4K | Wf
    char* ws = (char*)d_ws;
    ushort* xb0 = (ushort*)(ws);
    ushort* xb1 = (ushort*)(ws + 25600000);
    unsigned* packed = (unsigned*)xb1;
    int* rp = (int*)(ws + 51200000);
    int* col = (int*)(ws + 51200000 + 400128);
    int* bstart = (int*)(ws + 51200000 + 400128 + 6400000);
    int* bcnt = (int*)(ws + 51200000 + 400128 + 6400000 + 4096);
    int* bcur = (int*)(ws + 51200000 + 400128 + 6400000 + 8192);
    ushort* W10f = (ushort*)(ws + 51200000 + 400128 + 6400000 + 12288);
    ushort* W20f = W10f + 16384;
    ushort* W11f = W20f + 16384;
    ushort* W21f = W11f + 16384;
    ushort* W12f = W21f + 16384;
    ushort* W22f = W12f + 16384;

    // --- CSR build ---
    hipMemsetAsync(bcnt, 0, NB * sizeof(int), stream);
    bhist_k<<<NEB, 256, 0, stream>>>(ei + NE, bcnt);
    bscan_k<<<1, 1024, 0, stream>>>(bcnt, bstart, bcur);
    bscat_k<<<NEB, 256, 0, stream>>>(ei, bcur, packed);
    csr_k<<<NB, 256, 0, stream>>>(packed, bstart, rp, col);

    // --- converts ---
    cvtx_k<<<12500, 256, 0, stream>>>(x, xb0);
    packw_k<128><<<8, 256, 0, stream>>>(W1_0, W10f);
    packw_k<128><<<8, 256, 0, stream>>>(W2_0, W20f);
    packw_k<128><<<8, 256, 0, stream>>>(W1_1, W11f);
    packw_k<128><<<8, 256, 0, stream>>>(W2_1, W21f);
    packw_k<128><<<8, 256, 0, stream>>>(W1_2, W12f);
    packw_k<64><<<4, 256, 0, stream>>>(W2_2, W22f);

    const int GG = (NN + 63) / 64;  // 1563

    fused_k<128, 0><<<GG, 256, 0, stream>>>(xb0, rp, col, W10f, W20f, b1_0, b2_0, g0, be0, m0, v0, xb1, nullptr);
    fused_k<128, 0><<<GG, 256, 0, stream>>>(xb1, rp, col, W11f, W21f, b1_1, b2_1, g1, be1, m1, v1, xb0, nullptr);
    fused_k<64, 1><<<GG, 256, 0, stream>>>(xb0, rp, col, W12f, W22f, b1_2, b2_2, nullptr, nullptr, nullptr, nullptr, nullptr, out);
}

// Round 5
// 337.610 us; speedup vs baseline: 1.3291x; 1.3291x over previous
//
#include <hip/hip_runtime.h>
#include <math.h>

#define NN 100000
#define NE 1600000
#define BN_EPS 1e-5f
#define NB 782            // buckets of 128 nodes
#define EPB 4096
#define NEB ((NE + EPB - 1) / EPB)   // 391

typedef short bf16x8 __attribute__((ext_vector_type(8)));
typedef float f32x4 __attribute__((ext_vector_type(4)));
typedef unsigned short ushort;
typedef ushort us8 __attribute__((ext_vector_type(8)));
typedef ushort us4 __attribute__((ext_vector_type(4)));

__device__ __forceinline__ ushort f2bf(float f) {
    unsigned u = __float_as_uint(f);
    unsigned r = (u + 0x7FFFu + ((u >> 16) & 1u)) >> 16;
    return (ushort)r;
}
__device__ __forceinline__ float bf2f(ushort h) { return __uint_as_float(((unsigned)h) << 16); }

// ---------------- CSR build via dst-buckets ----------------
__global__ __launch_bounds__(256) void bhist_k(const int* __restrict__ dst, int* __restrict__ bcnt) {
    __shared__ int h[NB];
    for (int i = threadIdx.x; i < NB; i += 256) h[i] = 0;
    __syncthreads();
    int base = blockIdx.x * EPB;
    for (int i = threadIdx.x; i < EPB; i += 256) {
        int e = base + i;
        if (e < NE) atomicAdd(&h[dst[e] >> 7], 1);
    }
    __syncthreads();
    for (int i = threadIdx.x; i < NB; i += 256) {
        int c = h[i];
        if (c) atomicAdd(&bcnt[i], c);
    }
}

__global__ __launch_bounds__(1024) void bscan_k(const int* __restrict__ bcnt, int* __restrict__ bstart,
                                                int* __restrict__ bcur) {
    __shared__ int s[1024];
    int t = threadIdx.x;
    int v = (t < NB) ? bcnt[t] : 0;
    s[t] = v;
    __syncthreads();
    for (int off = 1; off < 1024; off <<= 1) {
        int u = (t >= off) ? s[t - off] : 0;
        __syncthreads();
        s[t] += u;
        __syncthreads();
    }
    int ex = s[t] - v;
    if (t <= NB) bstart[t] = ex;
    if (t < NB) bcur[t] = ex;
}

__global__ __launch_bounds__(256) void bscat_k(const int* __restrict__ ei, int* __restrict__ bcur,
                                               unsigned* __restrict__ packed) {
    __shared__ int h[NB];
    for (int i = threadIdx.x; i < NB; i += 256) h[i] = 0;
    __syncthreads();
    int base = blockIdx.x * EPB;
    for (int i = threadIdx.x; i < EPB; i += 256) {
        int e = base + i;
        if (e < NE) atomicAdd(&h[ei[NE + e] >> 7], 1);
    }
    __syncthreads();
    for (int i = threadIdx.x; i < NB; i += 256) {
        int c = h[i];
        if (c) h[i] = atomicAdd(&bcur[i], c);
    }
    __syncthreads();
    for (int i = threadIdx.x; i < EPB; i += 256) {
        int e = base + i;
        if (e < NE) {
            int d = ei[NE + e];
            int b = d >> 7;
            int pos = atomicAdd(&h[b], 1);
            packed[pos] = (unsigned)ei[e] | ((unsigned)(d & 127) << 17);
        }
    }
}

__global__ __launch_bounds__(256) void csr_k(const unsigned* __restrict__ packed,
                                             const int* __restrict__ bstart,
                                             int* __restrict__ rp, int* __restrict__ col) {
    __shared__ int hc[128], hb[128], sc[128];
    int t = threadIdx.x, b = blockIdx.x;
    int s0 = bstart[b], nb = bstart[b + 1] - s0;
    if (t < 128) hc[t] = 0;
    __syncthreads();
    for (int i = t; i < nb; i += 256) {
        unsigned u = packed[s0 + i];
        atomicAdd(&hc[u >> 17], 1);
    }
    __syncthreads();
    if (t < 128) sc[t] = hc[t];
    __syncthreads();
    for (int off = 1; off < 128; off <<= 1) {
        int u = 0;
        if (t < 128 && t >= off) u = sc[t - off];
        __syncthreads();
        if (t < 128) sc[t] += u;
        __syncthreads();
    }
    if (t < 128) {
        int ex = s0 + sc[t] - hc[t];
        int node = b * 128 + t;
        if (node < NN) rp[node] = ex;
        hb[t] = ex;
    }
    if (b == 0 && t == 0) rp[NN] = NE;
    __syncthreads();
    for (int i = t; i < nb; i += 256) {
        unsigned u = packed[s0 + i];
        int pos = atomicAdd(&hb[u >> 17], 1);
        col[pos] = (int)(u & 0x1FFFFu);
    }
}

// ---------------- converts ----------------
__global__ __launch_bounds__(256) void cvtx_k(const float* __restrict__ x, ushort* __restrict__ xb) {
    int i = blockIdx.x * 256 + threadIdx.x;
    float4 v = ((const float4*)x)[i];
    us4 o;
    o[0] = f2bf(v.x); o[1] = f2bf(v.y); o[2] = f2bf(v.z); o[3] = f2bf(v.w);
    ((us4*)xb)[i] = o;
}

// pack all 6 weight matrices -> fragment-linear bf16 in one launch.
// Wf[((kt*NT+nt)*64+l)*8+e] = W[(kt*32+(l>>4)*8+e)*DOUT + nt*16+(l&15)]
__global__ __launch_bounds__(256) void packall_k(
    const float* __restrict__ Wa, const float* __restrict__ Wb, const float* __restrict__ Wc,
    const float* __restrict__ Wd, const float* __restrict__ We, const float* __restrict__ Wf_,
    ushort* __restrict__ Fa, ushort* __restrict__ Fb, ushort* __restrict__ Fc,
    ushort* __restrict__ Fd, ushort* __restrict__ Fe, ushort* __restrict__ Ff) {
    int which = blockIdx.x >> 3, sub = blockIdx.x & 7;
    const float* W; ushort* F; int DOUT = 128;
    switch (which) {
        case 0: W = Wa; F = Fa; break;
        case 1: W = Wb; F = Fb; break;
        case 2: W = Wc; F = Fc; break;
        case 3: W = Wd; F = Fd; break;
        case 4: W = We; F = Fe; break;
        default: W = Wf_; F = Ff; DOUT = 64; break;
    }
    int NT = DOUT / 16;
    int idx = sub * 256 + threadIdx.x;
    if (idx >= 4 * NT * 64) return;
    int l = idx & 63;
    int nt = (idx >> 6) % NT;
    int kt = idx / (NT * 64);
    int colw = nt * 16 + (l & 15);
    int k0 = kt * 32 + (l >> 4) * 8;
    us8 o;
#pragma unroll
    for (int e = 0; e < 8; ++e) o[e] = f2bf(W[(k0 + e) * DOUT + colw]);
    ((us8*)F)[idx] = o;
}

// ---------------- aggregation (bf16): agg[i] = x[i] + sum_{j->i} x[j] ----------------
// 16 threads/node, 16B chunk per lane; edge loop unrolled x4 (4 independent gathers in flight).
__global__ __launch_bounds__(256) void aggb_k(const ushort* __restrict__ x, const int* __restrict__ rp,
                                              const int* __restrict__ col, ushort* __restrict__ agg) {
    int node = blockIdx.x * 16 + (threadIdx.x >> 4);
    int ch = threadIdx.x & 15;
    const us8* __restrict__ xv = (const us8*)x;
    us8 self = xv[(size_t)node * 16 + ch];
    float a[8];
#pragma unroll
    for (int i = 0; i < 8; ++i) a[i] = bf2f(self[i]);
    int p = rp[node];
    const int pe = rp[node + 1];
    for (; p + 3 < pe; p += 4) {
        int s0 = col[p], s1 = col[p + 1], s2 = col[p + 2], s3 = col[p + 3];
        us8 v0 = xv[(size_t)s0 * 16 + ch];
        us8 v1 = xv[(size_t)s1 * 16 + ch];
        us8 v2 = xv[(size_t)s2 * 16 + ch];
        us8 v3 = xv[(size_t)s3 * 16 + ch];
#pragma unroll
        for (int i = 0; i < 8; ++i)
            a[i] += (bf2f(v0[i]) + bf2f(v1[i])) + (bf2f(v2[i]) + bf2f(v3[i]));
    }
    for (; p < pe; ++p) {
        int s0 = col[p];
        us8 v = xv[(size_t)s0 * 16 + ch];
#pragma unroll
        for (int i = 0; i < 8; ++i) a[i] += bf2f(v[i]);
    }
    us8 o;
#pragma unroll
    for (int i = 0; i < 8; ++i) o[i] = f2bf(a[i]);
    ((us8*)agg)[(size_t)node * 16 + ch] = o;
}

// ---------------- MLP: out = epi( relu(A@W1+b1) @ W2 + b2 ) ----------------
// 256 threads = 4 waves, 64 rows/block. A and h staged block-wide in swizzled LDS.
// Wave w owns hidden-col tiles {2w,2w+1}; W frags live in registers, reused over 4 row-tiles.
// FINAL=0: BN+relu+residual -> bf16 outb (DOUT=128). FINAL=1: log_softmax -> fp32 outf (DOUT=64).
template <int FINAL>
__global__ __launch_bounds__(256, FINAL ? 2 : 4) void mlp2_k(
    const ushort* __restrict__ A, const ushort* __restrict__ W1f, const ushort* __restrict__ W2f,
    const float* __restrict__ b1, const float* __restrict__ b2,
    const float* __restrict__ bng, const float* __restrict__ bnb,
    const float* __restrict__ bnm, const float* __restrict__ bnv,
    const ushort* __restrict__ xres, ushort* __restrict__ outb, float* __restrict__ outf) {
    __shared__ ushort Alds[8192];   // 16KB: 64 rows x 128 bf16, XOR-swizzled
    __shared__ ushort Hlds[8192];   // 16KB: h tile, same layout
    const int t = threadIdx.x;
    const int w = t >> 6, l = t & 63;
    const int lrow = l & 15, lchk = l >> 4;
    const int R0 = blockIdx.x * 64;

    // ---- stage A tile into LDS (coalesced global us8 reads) ----
#pragma unroll
    for (int j = 0; j < 4; ++j) {
        int i = t + 256 * j;             // us8 index in [0,1024)
        int row = i >> 4, chunk = i & 15;
        int grow = R0 + row;
        us8 v = {0, 0, 0, 0, 0, 0, 0, 0};
        if (grow < NN) v = ((const us8*)A)[(size_t)grow * 16 + chunk];
        int byte = (row * 256 + chunk * 16) ^ ((row & 7) << 4);
        *(us8*)((char*)Alds + byte) = v;
    }

    // W1 frags for this wave's 2 hidden-col tiles (loaded once, reused 4x)
    const bf16x8* __restrict__ w1p = (const bf16x8*)W1f;
    bf16x8 w1r[2][4];
#pragma unroll
    for (int ntl = 0; ntl < 2; ++ntl)
#pragma unroll
        for (int kt = 0; kt < 4; ++kt)
            w1r[ntl][kt] = w1p[(kt * 8 + (2 * w + ntl)) * 64 + l];

    __syncthreads();

    // ---- stage 1: h = relu(A @ W1 + b1), per row-tile mt ----
#pragma unroll
    for (int mt = 0; mt < 4; ++mt) {
        bf16x8 af[4];
#pragma unroll
        for (int kt = 0; kt < 4; ++kt) {
            int row = mt * 16 + lrow;
            int byte = (row * 256 + kt * 64 + lchk * 16) ^ ((row & 7) << 4);
            af[kt] = *(const bf16x8*)((char*)Alds + byte);
        }
        f32x4 acc[2] = {f32x4{0.f, 0.f, 0.f, 0.f}, f32x4{0.f, 0.f, 0.f, 0.f}};
#pragma unroll
        for (int kt = 0; kt < 4; ++kt)
#pragma unroll
            for (int ntl = 0; ntl < 2; ++ntl)
                acc[ntl] = __builtin_amdgcn_mfma_f32_16x16x32_bf16(af[kt], w1r[ntl][kt], acc[ntl], 0, 0, 0);
#pragma unroll
        for (int ntl = 0; ntl < 2; ++ntl) {
            int colb = (2 * w + ntl) * 16 + lrow;
            float bias = b1[colb];
#pragma unroll
            for (int r = 0; r < 4; ++r) {
                int rloc = mt * 16 + lchk * 4 + r;
                float hv = fmaxf(acc[ntl][r] + bias, 0.f);
                int byte = (rloc * 256 + colb * 2) ^ ((rloc & 7) << 4);
                *(ushort*)((char*)Hlds + byte) = f2bf(hv);
            }
        }
    }
    __syncthreads();

    // ---- stage 2 ----
    if constexpr (FINAL == 0) {
        const bf16x8* __restrict__ w2p = (const bf16x8*)W2f;
        bf16x8 w2r[2][4];
#pragma unroll
        for (int ntl = 0; ntl < 2; ++ntl)
#pragma unroll
            for (int kt = 0; kt < 4; ++kt)
                w2r[ntl][kt] = w2p[(kt * 8 + (2 * w + ntl)) * 64 + l];
        // per-col BN constants for this wave's slice
        float sc[2], of[2];
#pragma unroll
        for (int ntl = 0; ntl < 2; ++ntl) {
            int colb = (2 * w + ntl) * 16 + lrow;
            sc[ntl] = bng[colb] * rsqrtf(bnv[colb] + BN_EPS);
            of[ntl] = (b2[colb] - bnm[colb]) * sc[ntl] + bnb[colb];
        }
#pragma unroll
        for (int mt = 0; mt < 4; ++mt) {
            bf16x8 hf[4];
#pragma unroll
            for (int kt = 0; kt < 4; ++kt) {
                int row = mt * 16 + lrow;
                int byte = (row * 256 + kt * 64 + lchk * 16) ^ ((row & 7) << 4);
                hf[kt] = *(const bf16x8*)((char*)Hlds + byte);
            }
            f32x4 acc2[2] = {f32x4{0.f, 0.f, 0.f, 0.f}, f32x4{0.f, 0.f, 0.f, 0.f}};
#pragma unroll
            for (int kt = 0; kt < 4; ++kt)
#pragma unroll
                for (int ntl = 0; ntl < 2; ++ntl)
                    acc2[ntl] = __builtin_amdgcn_mfma_f32_16x16x32_bf16(hf[kt], w2r[ntl][kt], acc2[ntl], 0, 0, 0);
#pragma unroll
            for (int ntl = 0; ntl < 2; ++ntl) {
                int colb = (2 * w + ntl) * 16 + lrow;
#pragma unroll
                for (int r = 0; r < 4; ++r) {
                    int grow = R0 + mt * 16 + lchk * 4 + r;
                    if (grow < NN) {
                        float xr = bf2f(xres[(size_t)grow * 128 + colb]);
                        float o = fmaxf(acc2[ntl][r] * sc[ntl] + of[ntl], 0.f) + xr;
                        outb[(size_t)grow * 128 + colb] = f2bf(o);
                    }
                }
            }
        }
    } else {
        // DOUT=64: wave w handles row-tile mt=w with all 4 col tiles (row-local softmax)
        const bf16x8* __restrict__ w2p = (const bf16x8*)W2f;
        bf16x8 hf[4];
#pragma unroll
        for (int kt = 0; kt < 4; ++kt) {
            int row = w * 16 + lrow;
            int byte = (row * 256 + kt * 64 + lchk * 16) ^ ((row & 7) << 4);
            hf[kt] = *(const bf16x8*)((char*)Hlds + byte);
        }
        f32x4 acc2[4];
#pragma unroll
        for (int nt = 0; nt < 4; ++nt) acc2[nt] = f32x4{0.f, 0.f, 0.f, 0.f};
#pragma unroll
        for (int kt = 0; kt < 4; ++kt)
#pragma unroll
            for (int nt = 0; nt < 4; ++nt)
                acc2[nt] = __builtin_amdgcn_mfma_f32_16x16x32_bf16(hf[kt], w2p[(kt * 4 + nt) * 64 + l], acc2[nt], 0, 0, 0);
        float bb[4];
#pragma unroll
        for (int nt = 0; nt < 4; ++nt) bb[nt] = b2[nt * 16 + lrow];
#pragma unroll
        for (int r = 0; r < 4; ++r) {
            float v0 = acc2[0][r] + bb[0], v1 = acc2[1][r] + bb[1];
            float v2 = acc2[2][r] + bb[2], v3 = acc2[3][r] + bb[3];
            float mx = fmaxf(fmaxf(v0, v1), fmaxf(v2, v3));
            for (int d = 1; d < 16; d <<= 1) mx = fmaxf(mx, __shfl_xor(mx, d));
            float sm = expf(v0 - mx) + expf(v1 - mx) + expf(v2 - mx) + expf(v3 - mx);
            for (int d = 1; d < 16; d <<= 1) sm += __shfl_xor(sm, d);
            float L = mx + logf(sm);
            int grow = R0 + w * 16 + lchk * 4 + r;
            if (grow < NN) {
                outf[(size_t)grow * 64 + 0 + lrow] = v0 - L;
                outf[(size_t)grow * 64 + 16 + lrow] = v1 - L;
                outf[(size_t)grow * 64 + 32 + lrow] = v2 - L;
                outf[(size_t)grow * 64 + 48 + lrow] = v3 - L;
            }
        }
    }
}

extern "C" void kernel_launch(void* const* d_in, const int* in_sizes, int n_in,
                              void* d_out, int out_size, void* d_ws, size_t ws_size,
                              hipStream_t stream) {
    const float* x = (const float*)d_in[0];
    const int* ei = (const int*)d_in[1];
    const float* W1_0 = (const float*)d_in[2];
    const float* b1_0 = (const float*)d_in[3];
    const float* W2_0 = (const float*)d_in[4];
    const float* b2_0 = (const float*)d_in[5];
    const float* W1_1 = (const float*)d_in[6];
    const float* b1_1 = (const float*)d_in[7];
    const float* W2_1 = (const float*)d_in[8];
    const float* b2_1 = (const float*)d_in[9];
    const float* W1_2 = (const float*)d_in[10];
    const float* b1_2 = (const float*)d_in[11];
    const float* W2_2 = (const float*)d_in[12];
    const float* b2_2 = (const float*)d_in[13];
    const float* g0 = (const float*)d_in[14];
    const float* be0 = (const float*)d_in[15];
    const float* m0 = (const float*)d_in[16];
    const float* v0 = (const float*)d_in[17];
    const float* g1 = (const float*)d_in[18];
    const float* be1 = (const float*)d_in[19];
    const float* m1 = (const float*)d_in[20];
    const float* v1 = (const float*)d_in[21];
    float* out = (float*)d_out;

    // ws layout (bytes): xb0 25.6M | xb1 25.6M | aggh 25.6M (packed overlays aggh pre-layer0)
    // | rp 400,128 | col 6.4M | bstart 4K | bcnt 4K | bcur 4K | Wf
    char* ws = (char*)d_ws;
    ushort* xb0 = (ushort*)(ws);
    ushort* xb1 = (ushort*)(ws + 25600000);
    ushort* aggh = (ushort*)(ws + 51200000);
    unsigned* packed = (unsigned*)aggh;
    int* rp = (int*)(ws + 76800000);
    int* col = (int*)(ws + 76800000 + 400128);
    int* bstart = (int*)(ws + 76800000 + 400128 + 6400000);
    int* bcnt = (int*)(ws + 76800000 + 400128 + 6400000 + 4096);
    int* bcur = (int*)(ws + 76800000 + 400128 + 6400000 + 8192);
    ushort* W10f = (ushort*)(ws + 76800000 + 400128 + 6400000 + 12288);
    ushort* W20f = W10f + 16384;
    ushort* W11f = W20f + 16384;
    ushort* W21f = W11f + 16384;
    ushort* W12f = W21f + 16384;
    ushort* W22f = W12f + 16384;

    // --- CSR build ---
    hipMemsetAsync(bcnt, 0, NB * sizeof(int), stream);
    bhist_k<<<NEB, 256, 0, stream>>>(ei + NE, bcnt);
    bscan_k<<<1, 1024, 0, stream>>>(bcnt, bstart, bcur);
    bscat_k<<<NEB, 256, 0, stream>>>(ei, bcur, packed);
    csr_k<<<NB, 256, 0, stream>>>(packed, bstart, rp, col);

    // --- converts ---
    cvtx_k<<<12500, 256, 0, stream>>>(x, xb0);
    packall_k<<<48, 256, 0, stream>>>(W1_0, W2_0, W1_1, W2_1, W1_2, W2_2,
                                      W10f, W20f, W11f, W21f, W12f, W22f);

    const int GA = NN / 16;         // 6250
    const int GG = (NN + 63) / 64;  // 1563

    // layer 0
    aggb_k<<<GA, 256, 0, stream>>>(xb0, rp, col, aggh);
    mlp2_k<0><<<GG, 256, 0, stream>>>(aggh, W10f, W20f, b1_0, b2_0, g0, be0, m0, v0, xb0, xb1, nullptr);
    // layer 1
    aggb_k<<<GA, 256, 0, stream>>>(xb1, rp, col, aggh);
    mlp2_k<0><<<GG, 256, 0, stream>>>(aggh, W11f, W21f, b1_1, b2_1, g1, be1, m1, v1, xb1, xb0, nullptr);
    // layer 2
    aggb_k<<<GA, 256, 0, stream>>>(xb0, rp, col, aggh);
    mlp2_k<1><<<GG, 256, 0, stream>>>(aggh, W12f, W22f, b1_2, b2_2, nullptr, nullptr, nullptr, nullptr, nullptr, nullptr, out);
}

// Round 6
// 297.098 us; speedup vs baseline: 1.5103x; 1.1364x over previous
//
#include <hip/hip_runtime.h>
#include <math.h>

#define NN 100000
#define NE 1600000
#define BN_EPS 1e-5f
#define NB 782            // buckets of 128 nodes
#define BCAP 4096         // fixed bucket capacity (avg 2046, sigma 45)
#define EPB 4096
#define NEB ((NE + EPB - 1) / EPB)   // 391

typedef short bf16x8 __attribute__((ext_vector_type(8)));
typedef float f32x4 __attribute__((ext_vector_type(4)));
typedef unsigned short ushort;
typedef ushort us8 __attribute__((ext_vector_type(8)));
typedef ushort us4 __attribute__((ext_vector_type(4)));

__device__ __forceinline__ ushort f2bf(float f) {
    unsigned u = __float_as_uint(f);
    unsigned r = (u + 0x7FFFu + ((u >> 16) & 1u)) >> 16;
    return (ushort)r;
}
__device__ __forceinline__ float bf2f(ushort h) { return __uint_as_float(((unsigned)h) << 16); }

// ---------------- CSR build: fixed-capacity dst-buckets ----------------
__global__ __launch_bounds__(1024) void binit_k(int* __restrict__ bcur) {
    int t = threadIdx.x;
    if (t < NB) bcur[t] = t << 12;   // t * BCAP
}

__global__ __launch_bounds__(256) void bscat_k(const int* __restrict__ ei, int* __restrict__ bcur,
                                               unsigned* __restrict__ packed) {
    __shared__ int h[NB];
    for (int i = threadIdx.x; i < NB; i += 256) h[i] = 0;
    __syncthreads();
    int base = blockIdx.x * EPB;
    for (int i = threadIdx.x; i < EPB; i += 256) {
        int e = base + i;
        if (e < NE) atomicAdd(&h[ei[NE + e] >> 7], 1);
    }
    __syncthreads();
    for (int i = threadIdx.x; i < NB; i += 256) {
        int c = h[i];
        if (c) h[i] = atomicAdd(&bcur[i], c);   // reserve contiguous range in bucket
    }
    __syncthreads();
    for (int i = threadIdx.x; i < EPB; i += 256) {
        int e = base + i;
        if (e < NE) {
            int d = ei[NE + e];
            int b = d >> 7;
            int pos = atomicAdd(&h[b], 1);
            packed[pos] = (unsigned)ei[e] | ((unsigned)(d & 127) << 17);
        }
    }
}

// per-bucket in-LDS counting sort; writes col in place over packed; emits rpS/rpE
__global__ __launch_bounds__(256) void csr_k(unsigned* __restrict__ packed,
                                             const int* __restrict__ bcur,
                                             int* __restrict__ rpS, int* __restrict__ rpE) {
    __shared__ unsigned ent[BCAP];     // 16 KB
    __shared__ int hc[128], hb[128], sc[128];
    int t = threadIdx.x, b = blockIdx.x;
    int base = b << 12;
    int nb = bcur[b] - base;
    if (nb > BCAP) nb = BCAP;
    for (int i = t; i < nb; i += 256) ent[i] = packed[base + i];
    if (t < 128) hc[t] = 0;
    __syncthreads();
    for (int i = t; i < nb; i += 256) atomicAdd(&hc[ent[i] >> 17], 1);
    __syncthreads();
    if (t < 128) sc[t] = hc[t];
    __syncthreads();
    for (int off = 1; off < 128; off <<= 1) {
        int u = 0;
        if (t < 128 && t >= off) u = sc[t - off];
        __syncthreads();
        if (t < 128) sc[t] += u;
        __syncthreads();
    }
    if (t < 128) {
        int ex = sc[t] - hc[t];
        int node = b * 128 + t;
        if (node < NN) {
            rpS[node] = base + ex;
            rpE[node] = base + ex + hc[t];
        }
        hb[t] = ex;
    }
    __syncthreads();
    for (int i = t; i < nb; i += 256) {
        unsigned u = ent[i];
        int pos = atomicAdd(&hb[u >> 17], 1);
        packed[base + pos] = u & 0x1FFFFu;
    }
}

// ---------------- converts ----------------
__global__ __launch_bounds__(256) void cvtx_k(const float* __restrict__ x, ushort* __restrict__ xb) {
    int i = blockIdx.x * 256 + threadIdx.x;
    float4 v = ((const float4*)x)[i];
    us4 o;
    o[0] = f2bf(v.x); o[1] = f2bf(v.y); o[2] = f2bf(v.z); o[3] = f2bf(v.w);
    ((us4*)xb)[i] = o;
}

// pack all 6 weight matrices -> fragment-linear bf16 in one launch
__global__ __launch_bounds__(256) void packall_k(
    const float* __restrict__ Wa, const float* __restrict__ Wb, const float* __restrict__ Wc,
    const float* __restrict__ Wd, const float* __restrict__ We, const float* __restrict__ Wf_,
    ushort* __restrict__ Fa, ushort* __restrict__ Fb, ushort* __restrict__ Fc,
    ushort* __restrict__ Fd, ushort* __restrict__ Fe, ushort* __restrict__ Ff) {
    int which = blockIdx.x >> 3, sub = blockIdx.x & 7;
    const float* W; ushort* F; int DOUT = 128;
    switch (which) {
        case 0: W = Wa; F = Fa; break;
        case 1: W = Wb; F = Fb; break;
        case 2: W = Wc; F = Fc; break;
        case 3: W = Wd; F = Fd; break;
        case 4: W = We; F = Fe; break;
        default: W = Wf_; F = Ff; DOUT = 64; break;
    }
    int NT = DOUT / 16;
    int idx = sub * 256 + threadIdx.x;
    if (idx >= 4 * NT * 64) return;
    int l = idx & 63;
    int nt = (idx >> 6) % NT;
    int kt = idx / (NT * 64);
    int colw = nt * 16 + (l & 15);
    int k0 = kt * 32 + (l >> 4) * 8;
    us8 o;
#pragma unroll
    for (int e = 0; e < 8; ++e) o[e] = f2bf(W[(k0 + e) * DOUT + colw]);
    ((us8*)F)[idx] = o;
}

// ---------------- aggregation (bf16), 8 gathers in flight per lane ----------------
__global__ __launch_bounds__(256) void aggb_k(const ushort* __restrict__ x, const int* __restrict__ rpS,
                                              const int* __restrict__ rpE, const unsigned* __restrict__ col,
                                              ushort* __restrict__ agg) {
    int node = blockIdx.x * 16 + (threadIdx.x >> 4);
    int ch = threadIdx.x & 15;
    const us8* __restrict__ xv = (const us8*)x;
    us8 self = xv[(size_t)node * 16 + ch];
    float a[8];
#pragma unroll
    for (int i = 0; i < 8; ++i) a[i] = bf2f(self[i]);
    int p = rpS[node];
    const int pe = rpE[node];
    for (; p + 7 < pe; p += 8) {
        unsigned s[8];
#pragma unroll
        for (int u = 0; u < 8; ++u) s[u] = col[p + u];
        us8 v[8];
#pragma unroll
        for (int u = 0; u < 8; ++u) v[u] = xv[(size_t)s[u] * 16 + ch];
#pragma unroll
        for (int i = 0; i < 8; ++i)
            a[i] += ((bf2f(v[0][i]) + bf2f(v[1][i])) + (bf2f(v[2][i]) + bf2f(v[3][i]))) +
                    ((bf2f(v[4][i]) + bf2f(v[5][i])) + (bf2f(v[6][i]) + bf2f(v[7][i])));
    }
    for (; p + 3 < pe; p += 4) {
        unsigned s0 = col[p], s1 = col[p + 1], s2 = col[p + 2], s3 = col[p + 3];
        us8 v0 = xv[(size_t)s0 * 16 + ch];
        us8 v1 = xv[(size_t)s1 * 16 + ch];
        us8 v2 = xv[(size_t)s2 * 16 + ch];
        us8 v3 = xv[(size_t)s3 * 16 + ch];
#pragma unroll
        for (int i = 0; i < 8; ++i)
            a[i] += (bf2f(v0[i]) + bf2f(v1[i])) + (bf2f(v2[i]) + bf2f(v3[i]));
    }
    for (; p < pe; ++p) {
        unsigned s0 = col[p];
        us8 v = xv[(size_t)s0 * 16 + ch];
#pragma unroll
        for (int i = 0; i < 8; ++i) a[i] += bf2f(v[i]);
    }
    us8 o;
#pragma unroll
    for (int i = 0; i < 8; ++i) o[i] = f2bf(a[i]);
    ((us8*)agg)[(size_t)node * 16 + ch] = o;
}

// ---------------- MLP: out = epi( relu(A@W1+b1) @ W2 + b2 ) ----------------
// 4 waves, 64 rows/block; A,h in swizzled LDS; W frags in registers.
// FINAL=0: BN+relu+residual via LDS repack -> coalesced us8 stores.
// FINAL=1: log_softmax -> fp32 outf (DOUT=64).
template <int FINAL>
__global__ __launch_bounds__(256, FINAL ? 2 : 4) void mlp2_k(
    const ushort* __restrict__ A, const ushort* __restrict__ W1f, const ushort* __restrict__ W2f,
    const float* __restrict__ b1, const float* __restrict__ b2,
    const float* __restrict__ bng, const float* __restrict__ bnb,
    const float* __restrict__ bnm, const float* __restrict__ bnv,
    const ushort* __restrict__ xres, ushort* __restrict__ outb, float* __restrict__ outf) {
    __shared__ ushort Alds[8192];   // 16KB: 64 x 128 bf16, XOR-swizzled
    __shared__ ushort Hlds[8192];
    const int t = threadIdx.x;
    const int w = t >> 6, l = t & 63;
    const int lrow = l & 15, lchk = l >> 4;
    const int R0 = blockIdx.x * 64;

    // ---- stage A tile into LDS ----
#pragma unroll
    for (int j = 0; j < 4; ++j) {
        int i = t + 256 * j;
        int row = i >> 4, chunk = i & 15;
        int grow = R0 + row;
        us8 v = {0, 0, 0, 0, 0, 0, 0, 0};
        if (grow < NN) v = ((const us8*)A)[(size_t)grow * 16 + chunk];
        int byte = (row * 256 + chunk * 16) ^ ((row & 7) << 4);
        *(us8*)((char*)Alds + byte) = v;
    }

    const bf16x8* __restrict__ w1p = (const bf16x8*)W1f;
    bf16x8 w1r[2][4];
#pragma unroll
    for (int ntl = 0; ntl < 2; ++ntl)
#pragma unroll
        for (int kt = 0; kt < 4; ++kt)
            w1r[ntl][kt] = w1p[(kt * 8 + (2 * w + ntl)) * 64 + l];

    __syncthreads();

    // ---- stage 1: h = relu(A @ W1 + b1) ----
#pragma unroll
    for (int mt = 0; mt < 4; ++mt) {
        bf16x8 af[4];
#pragma unroll
        for (int kt = 0; kt < 4; ++kt) {
            int row = mt * 16 + lrow;
            int byte = (row * 256 + kt * 64 + lchk * 16) ^ ((row & 7) << 4);
            af[kt] = *(const bf16x8*)((char*)Alds + byte);
        }
        f32x4 acc[2] = {f32x4{0.f, 0.f, 0.f, 0.f}, f32x4{0.f, 0.f, 0.f, 0.f}};
#pragma unroll
        for (int kt = 0; kt < 4; ++kt)
#pragma unroll
            for (int ntl = 0; ntl < 2; ++ntl)
                acc[ntl] = __builtin_amdgcn_mfma_f32_16x16x32_bf16(af[kt], w1r[ntl][kt], acc[ntl], 0, 0, 0);
#pragma unroll
        for (int ntl = 0; ntl < 2; ++ntl) {
            int colb = (2 * w + ntl) * 16 + lrow;
            float bias = b1[colb];
#pragma unroll
            for (int r = 0; r < 4; ++r) {
                int rloc = mt * 16 + lchk * 4 + r;
                float hv = fmaxf(acc[ntl][r] + bias, 0.f);
                int byte = (rloc * 256 + colb * 2) ^ ((rloc & 7) << 4);
                *(ushort*)((char*)Hlds + byte) = f2bf(hv);
            }
        }
    }
    __syncthreads();

    // ---- stage 2 ----
    if constexpr (FINAL == 0) {
        const bf16x8* __restrict__ w2p = (const bf16x8*)W2f;
        bf16x8 w2r[2][4];
#pragma unroll
        for (int ntl = 0; ntl < 2; ++ntl)
#pragma unroll
            for (int kt = 0; kt < 4; ++kt)
                w2r[ntl][kt] = w2p[(kt * 8 + (2 * w + ntl)) * 64 + l];
        float sc[2], of[2];
#pragma unroll
        for (int ntl = 0; ntl < 2; ++ntl) {
            int colb = (2 * w + ntl) * 16 + lrow;
            sc[ntl] = bng[colb] * rsqrtf(bnv[colb] + BN_EPS);
            of[ntl] = (b2[colb] - bnm[colb]) * sc[ntl] + bnb[colb];
        }
#pragma unroll
        for (int mt = 0; mt < 4; ++mt) {
            bf16x8 hf[4];
#pragma unroll
            for (int kt = 0; kt < 4; ++kt) {
                int row = mt * 16 + lrow;
                int byte = (row * 256 + kt * 64 + lchk * 16) ^ ((row & 7) << 4);
                hf[kt] = *(const bf16x8*)((char*)Hlds + byte);
            }
            f32x4 acc2[2] = {f32x4{0.f, 0.f, 0.f, 0.f}, f32x4{0.f, 0.f, 0.f, 0.f}};
#pragma unroll
            for (int kt = 0; kt < 4; ++kt)
#pragma unroll
                for (int ntl = 0; ntl < 2; ++ntl)
                    acc2[ntl] = __builtin_amdgcn_mfma_f32_16x16x32_bf16(hf[kt], w2r[ntl][kt], acc2[ntl], 0, 0, 0);
            // phase A: BN+relu -> bf16 into Alds (free after stage 1)
#pragma unroll
            for (int ntl = 0; ntl < 2; ++ntl) {
                int colb = (2 * w + ntl) * 16 + lrow;
#pragma unroll
                for (int r = 0; r < 4; ++r) {
                    int rloc = mt * 16 + lchk * 4 + r;
                    float o = fmaxf(acc2[ntl][r] * sc[ntl] + of[ntl], 0.f);
                    int byte = (rloc * 256 + colb * 2) ^ ((rloc & 7) << 4);
                    *(ushort*)((char*)Alds + byte) = f2bf(o);
                }
            }
        }
        __syncthreads();
        // phase B: repack -> coalesced us8 residual add + store
        const us8* __restrict__ xr8 = (const us8*)xres;
        us8* __restrict__ ob8 = (us8*)outb;
#pragma unroll
        for (int j = 0; j < 4; ++j) {
            int i = t + 256 * j;
            int row = i >> 4, chunk = i & 15;
            int grow = R0 + row;
            if (grow < NN) {
                int byte = (row * 256 + chunk * 16) ^ ((row & 7) << 4);
                us8 h8 = *(const us8*)((char*)Alds + byte);
                us8 r8 = xr8[(size_t)grow * 16 + chunk];
                us8 o8;
#pragma unroll
                for (int e = 0; e < 8; ++e) o8[e] = f2bf(bf2f(h8[e]) + bf2f(r8[e]));
                ob8[(size_t)grow * 16 + chunk] = o8;
            }
        }
    } else {
        // DOUT=64: wave w handles row-tile mt=w with all 4 col tiles (row-local softmax)
        const bf16x8* __restrict__ w2p = (const bf16x8*)W2f;
        bf16x8 hf[4];
#pragma unroll
        for (int kt = 0; kt < 4; ++kt) {
            int row = w * 16 + lrow;
            int byte = (row * 256 + kt * 64 + lchk * 16) ^ ((row & 7) << 4);
            hf[kt] = *(const bf16x8*)((char*)Hlds + byte);
        }
        f32x4 acc2[4];
#pragma unroll
        for (int nt = 0; nt < 4; ++nt) acc2[nt] = f32x4{0.f, 0.f, 0.f, 0.f};
#pragma unroll
        for (int kt = 0; kt < 4; ++kt)
#pragma unroll
            for (int nt = 0; nt < 4; ++nt)
                acc2[nt] = __builtin_amdgcn_mfma_f32_16x16x32_bf16(hf[kt], w2p[(kt * 4 + nt) * 64 + l], acc2[nt], 0, 0, 0);
        float bb[4];
#pragma unroll
        for (int nt = 0; nt < 4; ++nt) bb[nt] = b2[nt * 16 + lrow];
#pragma unroll
        for (int r = 0; r < 4; ++r) {
            float v0 = acc2[0][r] + bb[0], v1 = acc2[1][r] + bb[1];
            float v2 = acc2[2][r] + bb[2], v3 = acc2[3][r] + bb[3];
            float mx = fmaxf(fmaxf(v0, v1), fmaxf(v2, v3));
            for (int d = 1; d < 16; d <<= 1) mx = fmaxf(mx, __shfl_xor(mx, d));
            float sm = expf(v0 - mx) + expf(v1 - mx) + expf(v2 - mx) + expf(v3 - mx);
            for (int d = 1; d < 16; d <<= 1) sm += __shfl_xor(sm, d);
            float L = mx + logf(sm);
            int grow = R0 + w * 16 + lchk * 4 + r;
            if (grow < NN) {
                outf[(size_t)grow * 64 + 0 + lrow] = v0 - L;
                outf[(size_t)grow * 64 + 16 + lrow] = v1 - L;
                outf[(size_t)grow * 64 + 32 + lrow] = v2 - L;
                outf[(size_t)grow * 64 + 48 + lrow] = v3 - L;
            }
        }
    }
}

extern "C" void kernel_launch(void* const* d_in, const int* in_sizes, int n_in,
                              void* d_out, int out_size, void* d_ws, size_t ws_size,
                              hipStream_t stream) {
    const float* x = (const float*)d_in[0];
    const int* ei = (const int*)d_in[1];
    const float* W1_0 = (const float*)d_in[2];
    const float* b1_0 = (const float*)d_in[3];
    const float* W2_0 = (const float*)d_in[4];
    const float* b2_0 = (const float*)d_in[5];
    const float* W1_1 = (const float*)d_in[6];
    const float* b1_1 = (const float*)d_in[7];
    const float* W2_1 = (const float*)d_in[8];
    const float* b2_1 = (const float*)d_in[9];
    const float* W1_2 = (const float*)d_in[10];
    const float* b1_2 = (const float*)d_in[11];
    const float* W2_2 = (const float*)d_in[12];
    const float* b2_2 = (const float*)d_in[13];
    const float* g0 = (const float*)d_in[14];
    const float* be0 = (const float*)d_in[15];
    const float* m0 = (const float*)d_in[16];
    const float* v0 = (const float*)d_in[17];
    const float* g1 = (const float*)d_in[18];
    const float* be1 = (const float*)d_in[19];
    const float* m1 = (const float*)d_in[20];
    const float* v1 = (const float*)d_in[21];
    float* out = (float*)d_out;

    // ws layout (bytes): xb0 25.6M | xb1 25.6M | aggh 25.6M |
    // packed/col 12.8M (NB*BCAP*4 = 12,812,288) | rpS 400K | rpE 400K | bcur 4K | Wf
    char* ws = (char*)d_ws;
    ushort* xb0 = (ushort*)(ws);
    ushort* xb1 = (ushort*)(ws + 25600000);
    ushort* aggh = (ushort*)(ws + 51200000);
    unsigned* packed = (unsigned*)(ws + 76800000);     // also final col
    int* rpS = (int*)(ws + 76800000 + 12812288);
    int* rpE = (int*)(ws + 76800000 + 12812288 + 400128);
    int* bcur = (int*)(ws + 76800000 + 12812288 + 800256);
    ushort* W10f = (ushort*)(ws + 76800000 + 12812288 + 800256 + 4096);
    ushort* W20f = W10f + 16384;
    ushort* W11f = W20f + 16384;
    ushort* W21f = W11f + 16384;
    ushort* W12f = W21f + 16384;
    ushort* W22f = W12f + 16384;

    // --- CSR build (fixed-capacity buckets; no global scan) ---
    binit_k<<<1, 1024, 0, stream>>>(bcur);
    bscat_k<<<NEB, 256, 0, stream>>>(ei, bcur, packed);
    csr_k<<<NB, 256, 0, stream>>>(packed, bcur, rpS, rpE);

    // --- converts ---
    cvtx_k<<<12500, 256, 0, stream>>>(x, xb0);
    packall_k<<<48, 256, 0, stream>>>(W1_0, W2_0, W1_1, W2_1, W1_2, W2_2,
                                      W10f, W20f, W11f, W21f, W12f, W22f);

    const int GA = NN / 16;         // 6250
    const int GG = (NN + 63) / 64;  // 1563

    // layer 0
    aggb_k<<<GA, 256, 0, stream>>>(xb0, rpS, rpE, packed, aggh);
    mlp2_k<0><<<GG, 256, 0, stream>>>(aggh, W10f, W20f, b1_0, b2_0, g0, be0, m0, v0, xb0, xb1, nullptr);
    // layer 1
    aggb_k<<<GA, 256, 0, stream>>>(xb1, rpS, rpE, packed, aggh);
    mlp2_k<0><<<GG, 256, 0, stream>>>(aggh, W11f, W21f, b1_1, b2_1, g1, be1, m1, v1, xb1, xb0, nullptr);
    // layer 2
    aggb_k<<<GA, 256, 0, stream>>>(xb0, rpS, rpE, packed, aggh);
    mlp2_k<1><<<GG, 256, 0, stream>>>(aggh, W12f, W22f, b1_2, b2_2, nullptr, nullptr, nullptr, nullptr, nullptr, nullptr, out);
}